// Round 18
// baseline (80.189 us; speedup 1.0000x reference)
//
#include <hip/hip_runtime.h>

#define NJ   24
#define BLK  256
#define QMF4 (NJ * 4)           // float4 index of Qm ; +1 = Pm
#define INV4PI 0.07957747154594767f
#define FOURPI 12.566370614359172f

// ---------------------------------------------------------------------------
// K=1 quaternion kernel: one thread = one batch row, full 24-joint quat chain.
// No cross-lane combine at all. Joint records (4 float4, dense) in LDS, read
// wave-uniform (broadcast, conflict-free). hw v_sin/v_cos (revolutions).
// Minimal live state (~60 VGPR target) + __launch_bounds__(256,8) for 8
// waves/SIMD so the serial chain is covered by TLP and the kernel stays
// VALU-issue-bound (R17 evidence: the quat body is issue-limited).
// ---------------------------------------------------------------------------
__global__ __launch_bounds__(BLK, 8)
void poe_main(const float* __restrict__ x,
              const float* __restrict__ eta,
              const float* __restrict__ M,
              float* __restrict__ out,
              int nBatch)
{
    __shared__ float4 sC[NJ * 4 + 2];
    float* sF = (float*)sC;

    const int t = threadIdx.x;
    if (t < NJ) {
        const float w0 = eta[t*6+0], w1 = eta[t*6+1], w2 = eta[t*6+2];
        const float v0 = eta[t*6+3], v1 = eta[t*6+4], v2 = eta[t*6+5];
        const float k  = w0*w0 + w1*w1 + w2*w2;
        const bool  sm = (k < 1e-12f);
        const float invsqk = sm ? 0.0f : rsqrtf(k);
        const float sqk    = k * invsqk;
        const float invk   = invsqk * invsqk;
        const float invk15 = invk * invsqk;
        const float c10 = w1*v2 - w2*v1;
        const float c11 = w2*v0 - w0*v2;
        const float c12 = w0*v1 - w1*v0;
        const float c20 = w1*c12 - w2*c11;
        const float c21 = w2*c10 - w0*c12;
        const float c22 = w0*c11 - w1*c10;
        float* r = sF + t * 16;
        r[0]  = w0*invsqk;  r[1]  = w1*invsqk;  r[2]  = w2*invsqk;  r[3]  = sqk;
        r[4]  = v0;         r[5]  = v1;         r[6]  = v2;         r[7]  = sqk * INV4PI;
        r[8]  = c10*invk;   r[9]  = c11*invk;   r[10] = c12*invk;   r[11] = 0.0f;
        r[12] = c20*invk15; r[13] = c21*invk15; r[14] = c22*invk15; r[15] = 0.0f;
    } else if (t == NJ) {
        const float w0 = M[0], w1 = M[1], w2 = M[2];
        const float v0 = M[3], v1 = M[4], v2 = M[5];
        const float t2 = w0*w0 + w1*w1 + w2*w2;
        const bool  sm = (t2 < 1e-12f);
        const float t2s  = sm ? 1.0f : t2;
        const float invt = rsqrtf(t2s);
        const float th   = t2s * invt;
        float s, c;
        __sincosf(th, &s, &c);
        const float invt2 = invt * invt;
        const float B = sm ? 0.5f        : (1.0f - c) * invt2;
        const float C = sm ? (1.0f/6.0f) : (th - s) * invt2 * invt;
        float sh, chh;
        __sincosf(0.5f * th, &sh, &chh);
        const float axs = sm ? 0.5f : sh * invt;   // sin(th/2)/th (limit 1/2)
        float* r = sF + QMF4 * 4;
        r[0] = sm ? 1.0f : chh;
        r[1] = axs * w0;  r[2] = axs * w1;  r[3] = axs * w2;
        const float c10 = w1*v2 - w2*v1, c11 = w2*v0 - w0*v2, c12 = w0*v1 - w1*v0;
        const float c20 = w1*c12 - w2*c11, c21 = w2*c10 - w0*c12, c22 = w0*c11 - w1*c10;
        r[4] = v0 + B*c10 + C*c20;
        r[5] = v1 + B*c11 + C*c21;
        r[6] = v2 + B*c12 + C*c22;
        r[7] = 0.0f;
    }

    const int row = blockIdx.x * BLK + t;
    const bool active = row < nBatch;

    // ---- own 24 joint angles (6x float4, 16B-aligned 96B rows) ----
    float4 xz = make_float4(0.f,0.f,0.f,0.f);
    float4 x0=xz,x1=xz,x2=xz,x3=xz,x4=xz,x5=xz;
    if (active) {
        const float4* xr = (const float4*)(x + (size_t)row * NJ);
        x0=xr[0]; x1=xr[1]; x2=xr[2]; x3=xr[3]; x4=xr[4]; x5=xr[5];
    }

    __syncthreads();

    float Qw, Qx, Qy, Qz, p0, p1, p2;

#define JSTEP(JJ, A_, FIRST) do {                                             \
    const float4 A4 = sC[(JJ)*4 + 0];    /* wave-uniform broadcast reads */   \
    const float4 B4 = sC[(JJ)*4 + 1];                                         \
    const float4 C4 = sC[(JJ)*4 + 2];                                         \
    const float4 D4 = sC[(JJ)*4 + 3];                                         \
    const float a    = (A_);                                                  \
    const float hrev = a * B4.w;                                              \
    const float sh   = __builtin_amdgcn_sinf(hrev);                           \
    const float ch   = __builtin_amdgcn_cosf(hrev);                           \
    const float s    = 2.0f * sh * ch;          /* sin(phi)   */              \
    const float cB   = 2.0f * sh * sh;          /* 1-cos(phi) */              \
    const float g    = fmaf(FOURPI, hrev, -s);  /* phi-sin(phi) */            \
    const float qj0 = fmaf(a, B4.x, fmaf(cB, C4.x, g * D4.x));                \
    const float qj1 = fmaf(a, B4.y, fmaf(cB, C4.y, g * D4.y));                \
    const float qj2 = fmaf(a, B4.z, fmaf(cB, C4.z, g * D4.z));                \
    const float ex = sh * A4.x, ey = sh * A4.y, ez = sh * A4.z;               \
    if (FIRST) {                                                              \
        Qw = ch; Qx = ex; Qy = ey; Qz = ez;                                   \
        p0 = qj0; p1 = qj1; p2 = qj2;                                         \
    } else {                                                                  \
        const float u10 = Qy*qj2 - Qz*qj1;                                    \
        const float u11 = Qz*qj0 - Qx*qj2;                                    \
        const float u12 = Qx*qj1 - Qy*qj0;                                    \
        const float u20 = Qy*u12 - Qz*u11;                                    \
        const float u21 = Qz*u10 - Qx*u12;                                    \
        const float u22 = Qx*u11 - Qy*u10;                                    \
        const float tw  = 2.0f * Qw;                                          \
        p0 = fmaf(tw, u10, fmaf(2.0f, u20, p0 + qj0));                        \
        p1 = fmaf(tw, u11, fmaf(2.0f, u21, p1 + qj1));                        \
        p2 = fmaf(tw, u12, fmaf(2.0f, u22, p2 + qj2));                        \
        const float nQw = Qw*ch - Qx*ex - Qy*ey - Qz*ez;                      \
        const float nQx = Qw*ex + Qx*ch + Qy*ez - Qz*ey;                      \
        const float nQy = Qw*ey - Qx*ez + Qy*ch + Qz*ex;                      \
        const float nQz = Qw*ez + Qx*ey - Qy*ex + Qz*ch;                      \
        Qw=nQw; Qx=nQx; Qy=nQy; Qz=nQz;                                       \
    }                                                                         \
} while (0)

    JSTEP( 0, x0.x, true);
    JSTEP( 1, x0.y, false);
    JSTEP( 2, x0.z, false);
    JSTEP( 3, x0.w, false);
    JSTEP( 4, x1.x, false);
    JSTEP( 5, x1.y, false);
    JSTEP( 6, x1.z, false);
    JSTEP( 7, x1.w, false);
    JSTEP( 8, x2.x, false);
    JSTEP( 9, x2.y, false);
    JSTEP(10, x2.z, false);
    JSTEP(11, x2.w, false);
    JSTEP(12, x3.x, false);
    JSTEP(13, x3.y, false);
    JSTEP(14, x3.z, false);
    JSTEP(15, x3.w, false);
    JSTEP(16, x4.x, false);
    JSTEP(17, x4.y, false);
    JSTEP(18, x4.z, false);
    JSTEP(19, x4.w, false);
    JSTEP(20, x5.x, false);
    JSTEP(21, x5.y, false);
    JSTEP(22, x5.z, false);
    JSTEP(23, x5.w, false);
#undef JSTEP

    // ---- fold exp(M): T = T * Em ----
    {
        const float4 Qm = sC[QMF4];
        const float4 Pm = sC[QMF4 + 1];
        const float u10 = Qy*Pm.z - Qz*Pm.y;
        const float u11 = Qz*Pm.x - Qx*Pm.z;
        const float u12 = Qx*Pm.y - Qy*Pm.x;
        const float u20 = Qy*u12 - Qz*u11;
        const float u21 = Qz*u10 - Qx*u12;
        const float u22 = Qx*u11 - Qy*u10;
        const float tw  = 2.0f * Qw;
        p0 = fmaf(tw, u10, fmaf(2.0f, u20, p0 + Pm.x));
        p1 = fmaf(tw, u11, fmaf(2.0f, u21, p1 + Pm.y));
        p2 = fmaf(tw, u12, fmaf(2.0f, u22, p2 + Pm.z));
        const float nQw = Qw*Qm.x - Qx*Qm.y - Qy*Qm.z - Qz*Qm.w;
        const float nQx = Qw*Qm.y + Qx*Qm.x + Qy*Qm.w - Qz*Qm.z;
        const float nQy = Qw*Qm.z - Qx*Qm.w + Qy*Qm.x + Qz*Qm.y;
        const float nQz = Qw*Qm.w + Qx*Qm.z - Qy*Qm.y + Qz*Qm.x;
        Qw=nQw; Qx=nQx; Qy=nQy; Qz=nQz;
    }

    // ---- Q -> R, store full 4x4 ----
    if (active) {
        const float xx = Qx*Qx, yy = Qy*Qy, zz = Qz*Qz;
        const float xy = Qx*Qy, xz = Qx*Qz, yz = Qy*Qz;
        const float wx = Qw*Qx, wy = Qw*Qy, wz = Qw*Qz;
        float4* o = (float4*)(out + (size_t)row * 16);
        o[0] = make_float4(1.0f-2.0f*(yy+zz), 2.0f*(xy-wz),      2.0f*(xz+wy),      p0);
        o[1] = make_float4(2.0f*(xy+wz),      1.0f-2.0f*(xx+zz), 2.0f*(yz-wx),      p1);
        o[2] = make_float4(2.0f*(xz-wy),      2.0f*(yz+wx),      1.0f-2.0f*(xx+yy), p2);
        o[3] = make_float4(0.0f, 0.0f, 0.0f, 1.0f);
    }
}

extern "C" void kernel_launch(void* const* d_in, const int* in_sizes, int n_in,
                              void* d_out, int out_size, void* d_ws, size_t ws_size,
                              hipStream_t stream)
{
    const float* x   = (const float*)d_in[0];
    const float* eta = (const float*)d_in[1];
    const float* M   = (const float*)d_in[2];
    float* out = (float*)d_out;

    const int nBatch = in_sizes[0] / NJ;
    const int grid   = (nBatch + BLK - 1) / BLK;

    poe_main<<<grid, BLK, 0, stream>>>(x, eta, M, out, nBatch);
}

// Round 19
// 40.484 us; speedup vs baseline: 1.9807x; 1.9807x over previous
//
#include <hip/hip_runtime.h>

#define NJ   24
#define BLK  256
#define QMF4 (NJ * 4)           // float4 index of Qm ; +1 = Pm
#define INV4PI 0.07957747154594767f
#define FOURPI 12.566370614359172f

// ---------------------------------------------------------------------------
// K=1 quaternion kernel, spill-fixed: one thread = one batch row, 24-joint
// quat chain fully unrolled, joint records in LDS (wave-uniform broadcast
// reads), hw v_sin/v_cos. __launch_bounds__(256,4) -> 128 VGPR cap: the ~73
// live registers (24 angles + Q/p + record + temps) FIT, no scratch.
// R18's failure was the (256,8)=64-VGPR cap, not the K=1 structure.
// ---------------------------------------------------------------------------
__global__ __launch_bounds__(BLK, 4)
void poe_main(const float* __restrict__ x,
              const float* __restrict__ eta,
              const float* __restrict__ M,
              float* __restrict__ out,
              int nBatch)
{
    __shared__ float4 sC[NJ * 4 + 2];
    float* sF = (float*)sC;

    const int t = threadIdx.x;
    if (t < NJ) {
        const float w0 = eta[t*6+0], w1 = eta[t*6+1], w2 = eta[t*6+2];
        const float v0 = eta[t*6+3], v1 = eta[t*6+4], v2 = eta[t*6+5];
        const float k  = w0*w0 + w1*w1 + w2*w2;
        const bool  sm = (k < 1e-12f);
        const float invsqk = sm ? 0.0f : rsqrtf(k);
        const float sqk    = k * invsqk;
        const float invk   = invsqk * invsqk;
        const float invk15 = invk * invsqk;
        const float c10 = w1*v2 - w2*v1;
        const float c11 = w2*v0 - w0*v2;
        const float c12 = w0*v1 - w1*v0;
        const float c20 = w1*c12 - w2*c11;
        const float c21 = w2*c10 - w0*c12;
        const float c22 = w0*c11 - w1*c10;
        float* r = sF + t * 16;
        r[0]  = w0*invsqk;  r[1]  = w1*invsqk;  r[2]  = w2*invsqk;  r[3]  = sqk;
        r[4]  = v0;         r[5]  = v1;         r[6]  = v2;         r[7]  = sqk * INV4PI;
        r[8]  = c10*invk;   r[9]  = c11*invk;   r[10] = c12*invk;   r[11] = 0.0f;
        r[12] = c20*invk15; r[13] = c21*invk15; r[14] = c22*invk15; r[15] = 0.0f;
    } else if (t == NJ) {
        const float w0 = M[0], w1 = M[1], w2 = M[2];
        const float v0 = M[3], v1 = M[4], v2 = M[5];
        const float t2 = w0*w0 + w1*w1 + w2*w2;
        const bool  sm = (t2 < 1e-12f);
        const float t2s  = sm ? 1.0f : t2;
        const float invt = rsqrtf(t2s);
        const float th   = t2s * invt;
        float s, c;
        __sincosf(th, &s, &c);
        const float invt2 = invt * invt;
        const float B = sm ? 0.5f        : (1.0f - c) * invt2;
        const float C = sm ? (1.0f/6.0f) : (th - s) * invt2 * invt;
        float sh, chh;
        __sincosf(0.5f * th, &sh, &chh);
        const float axs = sm ? 0.5f : sh * invt;   // sin(th/2)/th (limit 1/2)
        float* r = sF + QMF4 * 4;
        r[0] = sm ? 1.0f : chh;
        r[1] = axs * w0;  r[2] = axs * w1;  r[3] = axs * w2;
        const float c10 = w1*v2 - w2*v1, c11 = w2*v0 - w0*v2, c12 = w0*v1 - w1*v0;
        const float c20 = w1*c12 - w2*c11, c21 = w2*c10 - w0*c12, c22 = w0*c11 - w1*c10;
        r[4] = v0 + B*c10 + C*c20;
        r[5] = v1 + B*c11 + C*c21;
        r[6] = v2 + B*c12 + C*c22;
        r[7] = 0.0f;
    }

    const int row = blockIdx.x * BLK + t;
    const bool active = row < nBatch;

    // ---- own 24 joint angles (6x float4, 16B-aligned 96B rows) ----
    float4 xz = make_float4(0.f,0.f,0.f,0.f);
    float4 x0=xz,x1=xz,x2=xz,x3=xz,x4=xz,x5=xz;
    if (active) {
        const float4* xr = (const float4*)(x + (size_t)row * NJ);
        x0=xr[0]; x1=xr[1]; x2=xr[2]; x3=xr[3]; x4=xr[4]; x5=xr[5];
    }

    __syncthreads();

    float Qw, Qx, Qy, Qz, p0, p1, p2;

#define JSTEP(JJ, A_, FIRST) do {                                             \
    const float4 A4 = sC[(JJ)*4 + 0];    /* wave-uniform broadcast reads */   \
    const float4 B4 = sC[(JJ)*4 + 1];                                         \
    const float4 C4 = sC[(JJ)*4 + 2];                                         \
    const float4 D4 = sC[(JJ)*4 + 3];                                         \
    const float a    = (A_);                                                  \
    const float hrev = a * B4.w;                                              \
    const float sh   = __builtin_amdgcn_sinf(hrev);                           \
    const float ch   = __builtin_amdgcn_cosf(hrev);                           \
    const float s    = 2.0f * sh * ch;          /* sin(phi)   */              \
    const float cB   = 2.0f * sh * sh;          /* 1-cos(phi) */              \
    const float g    = fmaf(FOURPI, hrev, -s);  /* phi-sin(phi) */            \
    const float qj0 = fmaf(a, B4.x, fmaf(cB, C4.x, g * D4.x));                \
    const float qj1 = fmaf(a, B4.y, fmaf(cB, C4.y, g * D4.y));                \
    const float qj2 = fmaf(a, B4.z, fmaf(cB, C4.z, g * D4.z));                \
    const float ex = sh * A4.x, ey = sh * A4.y, ez = sh * A4.z;               \
    if (FIRST) {                                                              \
        Qw = ch; Qx = ex; Qy = ey; Qz = ez;                                   \
        p0 = qj0; p1 = qj1; p2 = qj2;                                         \
    } else {                                                                  \
        const float u10 = Qy*qj2 - Qz*qj1;                                    \
        const float u11 = Qz*qj0 - Qx*qj2;                                    \
        const float u12 = Qx*qj1 - Qy*qj0;                                    \
        const float u20 = Qy*u12 - Qz*u11;                                    \
        const float u21 = Qz*u10 - Qx*u12;                                    \
        const float u22 = Qx*u11 - Qy*u10;                                    \
        const float tw  = 2.0f * Qw;                                          \
        p0 = fmaf(tw, u10, fmaf(2.0f, u20, p0 + qj0));                        \
        p1 = fmaf(tw, u11, fmaf(2.0f, u21, p1 + qj1));                        \
        p2 = fmaf(tw, u12, fmaf(2.0f, u22, p2 + qj2));                        \
        const float nQw = Qw*ch - Qx*ex - Qy*ey - Qz*ez;                      \
        const float nQx = Qw*ex + Qx*ch + Qy*ez - Qz*ey;                      \
        const float nQy = Qw*ey - Qx*ez + Qy*ch + Qz*ex;                      \
        const float nQz = Qw*ez + Qx*ey - Qy*ex + Qz*ch;                      \
        Qw=nQw; Qx=nQx; Qy=nQy; Qz=nQz;                                       \
    }                                                                         \
} while (0)

    JSTEP( 0, x0.x, true);
    JSTEP( 1, x0.y, false);
    JSTEP( 2, x0.z, false);
    JSTEP( 3, x0.w, false);
    JSTEP( 4, x1.x, false);
    JSTEP( 5, x1.y, false);
    JSTEP( 6, x1.z, false);
    JSTEP( 7, x1.w, false);
    JSTEP( 8, x2.x, false);
    JSTEP( 9, x2.y, false);
    JSTEP(10, x2.z, false);
    JSTEP(11, x2.w, false);
    JSTEP(12, x3.x, false);
    JSTEP(13, x3.y, false);
    JSTEP(14, x3.z, false);
    JSTEP(15, x3.w, false);
    JSTEP(16, x4.x, false);
    JSTEP(17, x4.y, false);
    JSTEP(18, x4.z, false);
    JSTEP(19, x4.w, false);
    JSTEP(20, x5.x, false);
    JSTEP(21, x5.y, false);
    JSTEP(22, x5.z, false);
    JSTEP(23, x5.w, false);
#undef JSTEP

    // ---- fold exp(M): T = T * Em ----
    {
        const float4 Qm = sC[QMF4];
        const float4 Pm = sC[QMF4 + 1];
        const float u10 = Qy*Pm.z - Qz*Pm.y;
        const float u11 = Qz*Pm.x - Qx*Pm.z;
        const float u12 = Qx*Pm.y - Qy*Pm.x;
        const float u20 = Qy*u12 - Qz*u11;
        const float u21 = Qz*u10 - Qx*u12;
        const float u22 = Qx*u11 - Qy*u10;
        const float tw  = 2.0f * Qw;
        p0 = fmaf(tw, u10, fmaf(2.0f, u20, p0 + Pm.x));
        p1 = fmaf(tw, u11, fmaf(2.0f, u21, p1 + Pm.y));
        p2 = fmaf(tw, u12, fmaf(2.0f, u22, p2 + Pm.z));
        const float nQw = Qw*Qm.x - Qx*Qm.y - Qy*Qm.z - Qz*Qm.w;
        const float nQx = Qw*Qm.y + Qx*Qm.x + Qy*Qm.w - Qz*Qm.z;
        const float nQy = Qw*Qm.z - Qx*Qm.w + Qy*Qm.x + Qz*Qm.y;
        const float nQz = Qw*Qm.w + Qx*Qm.z - Qy*Qm.y + Qz*Qm.x;
        Qw=nQw; Qx=nQx; Qy=nQy; Qz=nQz;
    }

    // ---- Q -> R, store full 4x4 ----
    if (active) {
        const float xx = Qx*Qx, yy = Qy*Qy, zz = Qz*Qz;
        const float xy = Qx*Qy, xz = Qx*Qz, yz = Qy*Qz;
        const float wx = Qw*Qx, wy = Qw*Qy, wz = Qw*Qz;
        float4* o = (float4*)(out + (size_t)row * 16);
        o[0] = make_float4(1.0f-2.0f*(yy+zz), 2.0f*(xy-wz),      2.0f*(xz+wy),      p0);
        o[1] = make_float4(2.0f*(xy+wz),      1.0f-2.0f*(xx+zz), 2.0f*(yz-wx),      p1);
        o[2] = make_float4(2.0f*(xz-wy),      2.0f*(yz+wx),      1.0f-2.0f*(xx+yy), p2);
        o[3] = make_float4(0.0f, 0.0f, 0.0f, 1.0f);
    }
}

extern "C" void kernel_launch(void* const* d_in, const int* in_sizes, int n_in,
                              void* d_out, int out_size, void* d_ws, size_t ws_size,
                              hipStream_t stream)
{
    const float* x   = (const float*)d_in[0];
    const float* eta = (const float*)d_in[1];
    const float* M   = (const float*)d_in[2];
    float* out = (float*)d_out;

    const int nBatch = in_sizes[0] / NJ;
    const int grid   = (nBatch + BLK - 1) / BLK;

    poe_main<<<grid, BLK, 0, stream>>>(x, eta, M, out, nBatch);
}